// Round 14
// baseline (126.478 us; speedup 1.0000x reference)
//
#include <hip/hip_runtime.h>
#include <hip/hip_fp16.h>
#include <math.h>

#define TH 256

typedef __attribute__((ext_vector_type(8))) short short8;
typedef __attribute__((ext_vector_type(4))) float floatx4;

// ---- LDS layout (shorts), 9376 sh = 18752 B -> target 8 blocks/CU ----
// P1 @0: 4 img * 1178 (odd-word stride).
// XS @4712 (4360 sh): x fp16 4*1090 during conv1; then time-multiplexed:
//   P2 @4712 (4*424) | BT @6408 (16*160, staged AFTER conv1 into dead x)
//   h1 @6408 (4*136, overwrites dead BT after conv2) | h2 @6952 (4*104)
//   LOG floats @3684f (sh 7368..7464, dead BT)
// W1B @9072: 150 broadcast half2 (uint idx 4536)
#define P1_S   0
#define XS_S   4712
#define P2_S   4712
#define BT_S   6408
#define H1_S   6408
#define H2_S   6952
#define LOGFI  3684       // float index
#define W1_U   4536       // uint index
#define LDS_F  4688       // 18752 B

static __device__ __forceinline__ unsigned short f2bf(float x) {
    union { float f; unsigned u; } v; v.f = x;
    return (unsigned short)((v.u + 0x7FFFu + ((v.u >> 16) & 1u)) >> 16);   // RNE
}
static __device__ __forceinline__ __half2 uash2(unsigned u) {
    union { unsigned u; __half2 h; } v; v.u = u; return v.h;
}
static __device__ __forceinline__ unsigned bfpack(unsigned hi, unsigned lo) {
    return __builtin_amdgcn_perm(hi, lo, 0x07060302u);   // 1x v_perm_b32 truncation
}
// weights row[kb..kb+7] -> bf16 frag; per-quad clamp keeps loads in bounds at the
// K tail (matching A slots are zero-padded).
static __device__ __forceinline__ short8 load_bf8t(const float* row, int kb, int K) {
    int b0 = (kb + 4 <= K) ? kb : (K - 8);
    int b1 = (kb + 8 <= K) ? (kb + 4) : (K - 8);
    uint4 w0 = *(const uint4*)(row + b0);
    uint4 w1 = *(const uint4*)(row + b1);
    union { int4 i; short8 s; } r;
    r.i.x = (int)bfpack(w0.y, w0.x);
    r.i.y = (int)bfpack(w0.w, w0.z);
    r.i.z = (int)bfpack(w1.y, w1.x);
    r.i.w = (int)bfpack(w1.w, w1.z);
    return r.s;
}

// NOTE: no min-waves arg (round 3: VGPR clamp -> scratch spill storm).
__global__ __launch_bounds__(TH) void lenet_kernel(
    const float* __restrict__ x,
    const float* __restrict__ w1,
    const float* __restrict__ w2g,
    const float* __restrict__ fw1,
    const float* __restrict__ fw2,
    const float* __restrict__ fc3w,
    const float* __restrict__ fc3b,
    float* __restrict__ out)
{
    __shared__ __align__(16) float sf[LDS_F];
    short* sh = (short*)sf;
    unsigned* su = (unsigned*)sf;
    const int* p1i = (const int*)sf;

    const int tid  = threadIdx.x;
    const int blk  = blockIdx.x;
    const int lane = tid & 63;
    const int wid  = tid >> 6;
    const int g    = lane >> 4;     // k-group selector of MFMA frags
    const int cn   = lane & 15;     // row(A)/col(B) selector

    // ---- prefetch all 4 images (4 float4/thread), stage x + w1 broadcast ----
    {
        float4 xreg[4];
        const float4* xg = (const float4*)(x + (size_t)blk * 4 * 1024);
        #pragma unroll
        for (int j = 0; j < 4; ++j) xreg[j] = xg[tid + j * TH];
        for (int e = tid; e < 150; e += TH)
            ((__half2*)(su + W1_U))[e] = __half2half2(__float2half(w1[e]));
        #pragma unroll
        for (int j = 0; j < 4; ++j) {
            int e = tid + j * TH;
            int m = e >> 8, rem = e & 255;
            int y = rem >> 3, k4 = rem & 7;
            // row stride 34 sh (17 words, odd) + img stride 1090 (545w, odd): conflict-free
            int off = XS_S + m * 1090 + y * 34 + k4 * 4;
            float4 v = xreg[j];
            *(__half2*)(sh + off)     = __floats2half2_rn(v.x, v.y);
            *(__half2*)(sh + off + 2) = __floats2half2_rn(v.z, v.w);
        }
    }
    __syncthreads();                                   // B1: x + w1 visible

    // ================= conv1 (packed fp16 VALU): 672 tasks, 2.6 passes =================
    for (int t = tid; t < 672; t += TH) {
        int m = t / 168, r = t - m * 168;
        int c = r % 6, q = r / 6;
        int i = q >> 1, hf = q & 1;
        const __half2* wb = (const __half2*)(su + W1_U) + c * 25;
        const int xbase = XS_S + m * 1090 + hf * 14;

        __half2 acc0[7], acc1[7];
        #pragma unroll
        for (int j = 0; j < 7; ++j) { acc0[j] = uash2(0u); acc1[j] = uash2(0u); }
        __half2 wprev[5];
        #pragma unroll
        for (int tt = 0; tt < 6; ++tt) {
            unsigned u[9];
            const unsigned* rp = (const unsigned*)(sh + xbase + (2 * i + tt) * 34);
            #pragma unroll
            for (int qq = 0; qq < 9; ++qq) u[qq] = rp[qq];
            __half2 p0[9], p1[8];
            #pragma unroll
            for (int qq = 0; qq < 9; ++qq) p0[qq] = uash2(u[qq]);
            #pragma unroll
            for (int qq = 0; qq < 8; ++qq)
                p1[qq] = uash2(__builtin_amdgcn_perm(u[qq + 1], u[qq], 0x05040302u));

            if (tt < 5) {
                __half2 wc[5];
                #pragma unroll
                for (int kx = 0; kx < 5; ++kx) wc[kx] = wb[tt * 5 + kx];
                #pragma unroll
                for (int j = 0; j < 7; ++j) {
                    acc0[j] = __hfma2(p0[j],     wc[0], acc0[j]);
                    acc0[j] = __hfma2(p1[j],     wc[1], acc0[j]);
                    acc0[j] = __hfma2(p0[j + 1], wc[2], acc0[j]);
                    acc0[j] = __hfma2(p1[j + 1], wc[3], acc0[j]);
                    acc0[j] = __hfma2(p0[j + 2], wc[4], acc0[j]);
                }
                if (tt >= 1) {
                    #pragma unroll
                    for (int j = 0; j < 7; ++j) {
                        acc1[j] = __hfma2(p0[j],     wprev[0], acc1[j]);
                        acc1[j] = __hfma2(p1[j],     wprev[1], acc1[j]);
                        acc1[j] = __hfma2(p0[j + 1], wprev[2], acc1[j]);
                        acc1[j] = __hfma2(p1[j + 1], wprev[3], acc1[j]);
                        acc1[j] = __hfma2(p0[j + 2], wprev[4], acc1[j]);
                    }
                }
                #pragma unroll
                for (int kx = 0; kx < 5; ++kx) wprev[kx] = wc[kx];
            } else {    // tt == 5: acc1 only, with w row 4 (in wprev)
                #pragma unroll
                for (int j = 0; j < 7; ++j) {
                    acc1[j] = __hfma2(p0[j],     wprev[0], acc1[j]);
                    acc1[j] = __hfma2(p1[j],     wprev[1], acc1[j]);
                    acc1[j] = __hfma2(p0[j + 1], wprev[2], acc1[j]);
                    acc1[j] = __hfma2(p1[j + 1], wprev[3], acc1[j]);
                    acc1[j] = __hfma2(p0[j + 2], wprev[4], acc1[j]);
                }
            }
        }
        short* dst = sh + P1_S + m * 1178 + i * 84 + hf * 42 + c;
        #pragma unroll
        for (int j = 0; j < 7; ++j) {
            float a0l = __half2float(__low2half(acc0[j]));
            float a0h = __half2float(__high2half(acc0[j]));
            float a1l = __half2float(__low2half(acc1[j]));
            float a1h = __half2float(__high2half(acc1[j]));
            float v = fmaxf(fmaxf(fmaxf(a0l, a0h), fmaxf(a1l, a1h)), 0.f);
            dst[j * 6] = (short)f2bf(v);
        }
    }
    __syncthreads();                                   // B2: p1 done, x dead

    // ---- stage BT (w2 bf16) into dead x region + p2 k-pad zeros ----
    // Bt[oc][s*32 + r], r = dx*6+ic (<30), zero-pad r=30,31; stride 160 (no pad)
    for (int e = tid; e < 2560; e += TH) {
        int oc = e / 160, kk = e - oc * 160;
        int s = kk >> 5, r = kk & 31;
        float v = 0.f;
        if (r < 30) v = w2g[oc * 150 + (r % 6) * 25 + s * 5 + (r / 6)];
        sh[BT_S + e] = (short)f2bf(v);
    }
    if (tid < 96) {                                    // p2 pads [400,424) = 0
        int im = tid / 24;
        sh[P2_S + im * 424 + 400 + (tid - im * 24)] = 0;
    }
    __syncthreads();                                   // B3: BT + pads visible

    // ===== conv2 via MFMA: M = img(4) x dy(2) x dx(2) = 16 rows, N=16 oc, K=5x32 =====
    {
        short8 Breg[5];
        #pragma unroll
        for (int s = 0; s < 5; ++s)
            Breg[s] = *(const short8*)(sh + BT_S + cn * 160 + s * 32 + 8 * g);

        const int aimg = cn & 3;
        const int ady  = (cn >> 2) & 1;
        const int adx  = cn >> 3;

        for (int w = wid; w < 25; w += 4) {            // pool windows (i,jx)
            int i = w / 5, jx = w - 5 * i;
            floatx4 acc = {0.f, 0.f, 0.f, 0.f};
            #pragma unroll
            for (int s = 0; s < 5; ++s) {
                int as = aimg * 1178 + (2 * i + ady + s) * 84 + (2 * jx + adx) * 6 + 8 * g;
                int ai = as >> 1;                      // 4B-aligned
                union { int4 i4; short8 s8; } a;
                a.i4.x = p1i[ai];     a.i4.y = p1i[ai + 1];
                a.i4.z = p1i[ai + 2]; a.i4.w = p1i[ai + 3];
                acc = __builtin_amdgcn_mfma_f32_16x16x32_bf16(a.s8, Breg[s], acc, 0, 0, 0);
            }
            // pool over (dy,dx) = over the 4 lane-groups: 2x shfl_xor; img = rg
            #pragma unroll
            for (int rg = 0; rg < 4; ++rg) {
                float v = acc[rg];
                v = fmaxf(v, __shfl_xor(v, 16));
                v = fmaxf(v, __shfl_xor(v, 32));
                if (g == 0)
                    sh[P2_S + rg * 424 + cn * 25 + i * 5 + jx] = (short)f2bf(fmaxf(v, 0.f));
            }
        }
    }
    __syncthreads();                                   // B4: p2 done, BT dead

    // ---- h1/h2 k-pad zeros (into dead BT region) ----
    if (tid < 64)  sh[H1_S + (tid >> 4) * 136 + 120 + (tid & 15)] = 0;
    if (tid >= 64 && tid < 144) {
        int e = tid - 64, im = e / 20;
        sh[H2_S + im * 104 + 84 + (e - im * 20)] = 0;
    }

    // ================= fc1 via MFMA: K=400(13 steps), N=120(8 tiles) =================
    for (int nt = wid; nt < 8; nt += 4) {
        floatx4 acc = {0.f, 0.f, 0.f, 0.f};
        int n = nt * 16 + cn;
        const float* wrow = fw1 + (size_t)(n < 120 ? n : 119) * 400;
        for (int ks = 0; ks < 13; ++ks) {
            int kb = ks * 32 + 8 * g;
            short8 b = load_bf8t(wrow, kb, 400);
            short8 a = *(const short8*)(sh + P2_S + (cn & 3) * 424 + kb);
            acc = __builtin_amdgcn_mfma_f32_16x16x32_bf16(a, b, acc, 0, 0, 0);
        }
        if (g == 0 && n < 120) {                       // C rows 0..3 = imgs
            #pragma unroll
            for (int rg = 0; rg < 4; ++rg)
                sh[H1_S + rg * 136 + n] = (short)f2bf(fmaxf(acc[rg], 0.f));
        }
    }
    __syncthreads();                                   // B5

    // ================= fc2 via MFMA: K=120(4 steps), N=84(6 tiles) =================
    for (int nt = wid; nt < 6; nt += 4) {
        floatx4 acc = {0.f, 0.f, 0.f, 0.f};
        int n = nt * 16 + cn;
        const float* wrow = fw2 + (size_t)(n < 84 ? n : 83) * 120;
        for (int ks = 0; ks < 4; ++ks) {
            int kb = ks * 32 + 8 * g;
            short8 b = load_bf8t(wrow, kb, 120);
            short8 a = *(const short8*)(sh + H1_S + (cn & 3) * 136 + kb);
            acc = __builtin_amdgcn_mfma_f32_16x16x32_bf16(a, b, acc, 0, 0, 0);
        }
        if (g == 0 && n < 84) {
            #pragma unroll
            for (int rg = 0; rg < 4; ++rg)
                sh[H2_S + rg * 104 + n] = (short)f2bf(fmaxf(acc[rg], 0.f));
        }
    }
    __syncthreads();                                   // B6

    // ================= fc3 via MFMA: K=84(3 steps), N=10 + bias =================
    if (wid == 0) {
        floatx4 acc = {0.f, 0.f, 0.f, 0.f};
        int n = cn;
        const float* wrow = fc3w + (size_t)(n < 10 ? n : 9) * 84;
        for (int ks = 0; ks < 3; ++ks) {
            int kb = ks * 32 + 8 * g;
            short8 b = load_bf8t(wrow, kb, 84);
            short8 a = *(const short8*)(sh + H2_S + (cn & 3) * 104 + kb);
            acc = __builtin_amdgcn_mfma_f32_16x16x32_bf16(a, b, acc, 0, 0, 0);
        }
        if (g == 0 && n < 10) {
            float bias = fc3b[n];
            #pragma unroll
            for (int rg = 0; rg < 4; ++rg)
                sf[LOGFI + rg * 12 + n] = acc[rg] + bias;
        }
    }
    __syncthreads();                                   // B7

    // ================= softmax, one thread per image =================
    if (tid < 4) {
        const float* lg = sf + LOGFI + tid * 12;
        float mx = lg[0];
        #pragma unroll
        for (int n = 1; n < 10; ++n) mx = fmaxf(mx, lg[n]);
        float e[10]; float sum = 0.f;
        #pragma unroll
        for (int n = 0; n < 10; ++n) { e[n] = expf(lg[n] - mx); sum += e[n]; }
        float inv = 1.f / sum;
        float* op = out + ((size_t)blk * 4 + tid) * 10;
        #pragma unroll
        for (int n = 0; n < 10; ++n) op[n] = e[n] * inv;
    }
}

extern "C" void kernel_launch(void* const* d_in, const int* in_sizes, int n_in,
                              void* d_out, int out_size, void* d_ws, size_t ws_size,
                              hipStream_t stream) {
    const float* x    = (const float*)d_in[0];
    const float* w1   = (const float*)d_in[1];
    const float* w2   = (const float*)d_in[2];
    const float* fw1  = (const float*)d_in[3];
    const float* fw2  = (const float*)d_in[4];
    const float* fc3w = (const float*)d_in[5];
    const float* fc3b = (const float*)d_in[6];
    float* outp = (float*)d_out;

    dim3 grid(16384 / 4), block(TH);
    hipLaunchKernelGGL(lenet_kernel, grid, block, 0, stream,
                       x, w1, w2, fw1, fw2, fc3w, fc3b, outp);
}

// Round 17
// 89.248 us; speedup vs baseline: 1.4171x; 1.4171x over previous
//
#include <hip/hip_runtime.h>
#include <hip/hip_fp16.h>
#include <math.h>

#define TH 512

typedef __attribute__((ext_vector_type(8))) _Float16 half8;
typedef __attribute__((ext_vector_type(4))) float floatx4;

// ---- LDS layout (shorts), 21132 sh = 42264 B -> 3 blocks/CU x 8 waves ----
// P1 @0: 8 img * 1178 fp16 (odd-word stride -> bank spread)
// X  @9424: 8 img * 1090 fp16 (row stride 34; dead after conv1)
//   P2 @9424 (8*424) aliases dead x after B2.
// BT @18144: 16 oc * 168 fp16 (w2: k = ky*32 + dx*6+ic, r>=30 -> 0); dead after conv2:
//   H1 @18144 (8*136) | H2 @19232 (8*104) | LOG floats @10032f (sh 20064..20160)
// W1B @20832: 150 broadcast half2 (uint idx 10416)
#define P1_S   0
#define X_S    9424
#define P2_S   9424
#define BT_S   18144
#define H1_S   18144
#define H2_S   19232
#define LOG_F  10032      // float index
#define W1_U   10416      // uint index
#define LDS_F  10566      // floats total = 42264 B

static __device__ __forceinline__ __half2 uash2(unsigned u) {
    union { unsigned u; __half2 h; } v; v.u = u; return v.h;
}
// weights row[kb..kb+7] -> fp16 frag via v_cvt_pkrtz (1 inst / 2 weights); per-quad
// clamp keeps loads in bounds at the K tail (matching A slots are zero-padded).
// NOTE: cvt_pkrtz returns __fp16x2; bit-cast through uint into the _Float16 vector.
static __device__ __forceinline__ half8 load_h8(const float* row, int kb, int K) {
    int b0 = (kb + 4 <= K) ? kb : (K - 8);
    int b1 = (kb + 8 <= K) ? (kb + 4) : (K - 8);
    float4 w0 = *(const float4*)(row + b0);
    float4 w1 = *(const float4*)(row + b1);
    union { unsigned u[4]; half8 v; } r;
    union { __fp16 __attribute__((ext_vector_type(2))) h; unsigned u; } c;
    c.h = __builtin_amdgcn_cvt_pkrtz(w0.x, w0.y); r.u[0] = c.u;
    c.h = __builtin_amdgcn_cvt_pkrtz(w0.z, w0.w); r.u[1] = c.u;
    c.h = __builtin_amdgcn_cvt_pkrtz(w1.x, w1.y); r.u[2] = c.u;
    c.h = __builtin_amdgcn_cvt_pkrtz(w1.z, w1.w); r.u[3] = c.u;
    return r.v;
}

// NOTE: no min-waves arg (round 3: VGPR clamp -> scratch spill storm).
__global__ __launch_bounds__(TH) void lenet_kernel(
    const float* __restrict__ x,
    const float* __restrict__ w1,
    const float* __restrict__ w2g,
    const float* __restrict__ fw1,
    const float* __restrict__ fw2,
    const float* __restrict__ fc3w,
    const float* __restrict__ fc3b,
    float* __restrict__ out)
{
    __shared__ __align__(16) float sf[LDS_F];
    short* sh = (short*)sf;
    __half* hp = (__half*)sf;
    unsigned* su = (unsigned*)sf;
    const int* p1i = (const int*)sf;

    const int tid  = threadIdx.x;
    const int blk  = blockIdx.x;
    const int lane = tid & 63;
    const int wid  = tid >> 6;      // 0..7
    const int g    = lane >> 4;     // k-group selector of MFMA frags
    const int cn   = lane & 15;     // row(A)/col(B) selector
    const int pr   = cn & 7;        // img row (conv2: rows 8..15 = dy=1 of imgs 0..7)
    const int dyr  = cn >> 3;       // conv2 pool-row packed into M

    // ---- prefetch all 8 images (4 float4/thread) + stage x, w1, BT ----
    {
        float4 xreg[4];
        const float4* xg = (const float4*)(x + (size_t)blk * 8 * 1024);
        #pragma unroll
        for (int j = 0; j < 4; ++j) xreg[j] = xg[tid + j * TH];

        for (int e = tid; e < 150; e += TH)
            ((__half2*)(su + W1_U))[e] = __half2half2(__float2half(w1[e]));
        // Bt[oc][ky*32 + r], r = dx*6+ic (<30), zero-pad r=30,31  (fp16)
        for (int e = tid; e < 2560; e += TH) {
            int oc = e / 160, kk = e - oc * 160;
            int s = kk >> 5, r = kk & 31;
            float v = 0.f;
            if (r < 30) v = w2g[oc * 150 + (r % 6) * 25 + s * 5 + (r / 6)];
            hp[BT_S + oc * 168 + kk] = __float2half(v);
        }
        #pragma unroll
        for (int j = 0; j < 4; ++j) {
            int e = tid + j * TH;                    // e < 2048
            int m = e >> 8, rem = e & 255;
            int y = rem >> 3, k4 = rem & 7;
            // row stride 34 sh (17 words, odd) + img stride 1090 (545w, odd): conflict-free
            int off = X_S + m * 1090 + y * 34 + k4 * 4;
            float4 v = xreg[j];
            *(__half2*)(sh + off)     = __floats2half2_rn(v.x, v.y);
            *(__half2*)(sh + off + 2) = __floats2half2_rn(v.z, v.w);
        }
    }
    __syncthreads();                                   // B1: x + w1 + BT visible

    // ================= conv1 (packed fp16 VALU): 1344 tasks = 2.625 passes =================
    for (int t = tid; t < 1344; t += TH) {
        int m = t / 168, r = t - m * 168;
        int c = r % 6, q = r / 6;
        int i = q >> 1, hf = q & 1;
        const __half2* wb = (const __half2*)(su + W1_U) + c * 25;
        const int xbase = X_S + m * 1090 + hf * 14;

        __half2 acc0[7], acc1[7];
        #pragma unroll
        for (int j = 0; j < 7; ++j) { acc0[j] = uash2(0u); acc1[j] = uash2(0u); }
        __half2 wprev[5];
        #pragma unroll
        for (int tt = 0; tt < 6; ++tt) {
            unsigned u[9];
            const unsigned* rp = (const unsigned*)(sh + xbase + (2 * i + tt) * 34);
            #pragma unroll
            for (int qq = 0; qq < 9; ++qq) u[qq] = rp[qq];
            __half2 p0[9], p1[8];
            #pragma unroll
            for (int qq = 0; qq < 9; ++qq) p0[qq] = uash2(u[qq]);
            #pragma unroll
            for (int qq = 0; qq < 8; ++qq)
                p1[qq] = uash2(__builtin_amdgcn_perm(u[qq + 1], u[qq], 0x05040302u));

            if (tt < 5) {
                __half2 wc[5];
                #pragma unroll
                for (int kx = 0; kx < 5; ++kx) wc[kx] = wb[tt * 5 + kx];
                #pragma unroll
                for (int j = 0; j < 7; ++j) {
                    acc0[j] = __hfma2(p0[j],     wc[0], acc0[j]);
                    acc0[j] = __hfma2(p1[j],     wc[1], acc0[j]);
                    acc0[j] = __hfma2(p0[j + 1], wc[2], acc0[j]);
                    acc0[j] = __hfma2(p1[j + 1], wc[3], acc0[j]);
                    acc0[j] = __hfma2(p0[j + 2], wc[4], acc0[j]);
                }
                if (tt >= 1) {
                    #pragma unroll
                    for (int j = 0; j < 7; ++j) {
                        acc1[j] = __hfma2(p0[j],     wprev[0], acc1[j]);
                        acc1[j] = __hfma2(p1[j],     wprev[1], acc1[j]);
                        acc1[j] = __hfma2(p0[j + 1], wprev[2], acc1[j]);
                        acc1[j] = __hfma2(p1[j + 1], wprev[3], acc1[j]);
                        acc1[j] = __hfma2(p0[j + 2], wprev[4], acc1[j]);
                    }
                }
                #pragma unroll
                for (int kx = 0; kx < 5; ++kx) wprev[kx] = wc[kx];
            } else {    // tt == 5: acc1 only, with w row 4 (in wprev)
                #pragma unroll
                for (int j = 0; j < 7; ++j) {
                    acc1[j] = __hfma2(p0[j],     wprev[0], acc1[j]);
                    acc1[j] = __hfma2(p1[j],     wprev[1], acc1[j]);
                    acc1[j] = __hfma2(p0[j + 1], wprev[2], acc1[j]);
                    acc1[j] = __hfma2(p1[j + 1], wprev[3], acc1[j]);
                    acc1[j] = __hfma2(p0[j + 2], wprev[4], acc1[j]);
                }
            }
        }
        __half* dst = hp + P1_S + m * 1178 + i * 84 + hf * 42 + c;
        #pragma unroll
        for (int j = 0; j < 7; ++j) {
            // fp32 epilogue max (ROCm 7.2 lacks __hmax2/__hmax overloads); store fp16
            float a0l = __half2float(__low2half(acc0[j]));
            float a0h = __half2float(__high2half(acc0[j]));
            float a1l = __half2float(__low2half(acc1[j]));
            float a1h = __half2float(__high2half(acc1[j]));
            float v = fmaxf(fmaxf(fmaxf(a0l, a0h), fmaxf(a1l, a1h)), 0.f);
            dst[j * 6] = __float2half(v);
        }
    }
    __syncthreads();                                   // B2: p1 done, x dead

    // ===== conv2 via f16 MFMA, dy-packed: M = img(8) x dy(2), N=16 oc, K=5x32 =====
    {
        half8 Breg[5];
        #pragma unroll
        for (int s = 0; s < 5; ++s)
            Breg[s] = *(const half8*)(sh + BT_S + cn * 168 + s * 32 + 8 * g);

        if (tid < 192) {                               // p2 k-pad zeros [400,424)
            int im = tid / 24;
            sh[P2_S + im * 424 + 400 + (tid - im * 24)] = 0;
        }

        for (int w = wid; w < 25; w += 8) {            // pool windows (i,jx)
            int i = w / 5, jx = w - 5 * i;
            floatx4 a0 = {0.f,0.f,0.f,0.f}, a1 = {0.f,0.f,0.f,0.f};
            #pragma unroll
            for (int s = 0; s < 5; ++s) {
                #pragma unroll
                for (int dxp = 0; dxp < 2; ++dxp) {
                    int as = pr * 1178 + (2 * i + dyr + s) * 84 + (2 * jx + dxp) * 6 + 8 * g;
                    int ai = as >> 1;                  // 4B-aligned
                    union { int4 i4; half8 h8; } a;
                    a.i4.x = p1i[ai];     a.i4.y = p1i[ai + 1];
                    a.i4.z = p1i[ai + 2]; a.i4.w = p1i[ai + 3];
                    floatx4* acc = dxp == 0 ? &a0 : &a1;
                    *acc = __builtin_amdgcn_mfma_f32_16x16x32_f16(a.h8, Breg[s], *acc, 0, 0, 0);
                }
            }
            // pool: in-lane dx max, cross-row dy max (row r vs r+8 = lane xor 32)
            #pragma unroll
            for (int rg = 0; rg < 4; ++rg) {
                float v = fmaxf(a0[rg], a1[rg]);
                v = fmaxf(v, __shfl_xor(v, 32));
                if (g < 2) {
                    int im = 4 * g + rg;
                    hp[P2_S + im * 424 + cn * 25 + i * 5 + jx] = __float2half(fmaxf(v, 0.f));
                }
            }
        }
    }
    __syncthreads();                                   // B3: p2 done, BT dead

    // ================= fc1 via f16 MFMA: K=400(13 steps), 8 tiles = 1/wave =================
    {
        if (tid < 128)                                 // h1 pad zeros [120,136)
            sh[H1_S + (tid >> 4) * 136 + 120 + (tid & 15)] = 0;
        if (tid >= 128 && tid < 288) {                 // h2 pad zeros [84,104)
            int e = tid - 128, im = e / 20;
            sh[H2_S + im * 104 + 84 + (e - im * 20)] = 0;
        }
        int nt = wid;
        floatx4 acc = {0.f,0.f,0.f,0.f};
        int n = nt * 16 + cn;
        const float* wrow = fw1 + (size_t)(n < 120 ? n : 119) * 400;
        for (int ks = 0; ks < 13; ++ks) {
            int kb = ks * 32 + 8 * g;
            half8 b = load_h8(wrow, kb, 400);
            half8 a = *(const half8*)(sh + P2_S + pr * 424 + kb);
            acc = __builtin_amdgcn_mfma_f32_16x16x32_f16(a, b, acc, 0, 0, 0);
        }
        if (g < 2 && n < 120) {
            #pragma unroll
            for (int rg = 0; rg < 4; ++rg)
                hp[H1_S + (4 * g + rg) * 136 + n] = __float2half(fmaxf(acc[rg], 0.f));
        }
    }
    __syncthreads();                                   // B4

    // ================= fc2 via f16 MFMA: K=120(4 steps), 6 tiles on waves 0-5 =================
    if (wid < 6) {
        floatx4 acc = {0.f,0.f,0.f,0.f};
        int n = wid * 16 + cn;
        const float* wrow = fw2 + (size_t)(n < 84 ? n : 83) * 120;
        for (int ks = 0; ks < 4; ++ks) {
            int kb = ks * 32 + 8 * g;
            half8 b = load_h8(wrow, kb, 120);
            half8 a = *(const half8*)(sh + H1_S + pr * 136 + kb);
            acc = __builtin_amdgcn_mfma_f32_16x16x32_f16(a, b, acc, 0, 0, 0);
        }
        if (g < 2 && n < 84) {
            #pragma unroll
            for (int rg = 0; rg < 4; ++rg)
                hp[H2_S + (4 * g + rg) * 104 + n] = __float2half(fmaxf(acc[rg], 0.f));
        }
    }
    __syncthreads();                                   // B5

    // ================= fc3 via f16 MFMA: K=84(3 steps), N=10 + bias =================
    if (wid == 0) {
        floatx4 acc = {0.f,0.f,0.f,0.f};
        int n = cn;
        const float* wrow = fc3w + (size_t)(n < 10 ? n : 9) * 84;
        for (int ks = 0; ks < 3; ++ks) {
            int kb = ks * 32 + 8 * g;
            half8 b = load_h8(wrow, kb, 84);
            half8 a = *(const half8*)(sh + H2_S + pr * 104 + kb);
            acc = __builtin_amdgcn_mfma_f32_16x16x32_f16(a, b, acc, 0, 0, 0);
        }
        if (g < 2 && n < 10) {
            float bias = fc3b[n];
            #pragma unroll
            for (int rg = 0; rg < 4; ++rg)
                sf[LOG_F + (4 * g + rg) * 12 + n] = acc[rg] + bias;
        }
    }
    __syncthreads();                                   // B6

    // ================= softmax, one thread per image =================
    if (tid < 8) {
        const float* lg = sf + LOG_F + tid * 12;
        float mx = lg[0];
        #pragma unroll
        for (int n = 1; n < 10; ++n) mx = fmaxf(mx, lg[n]);
        float e[10]; float sum = 0.f;
        #pragma unroll
        for (int n = 0; n < 10; ++n) { e[n] = expf(lg[n] - mx); sum += e[n]; }
        float inv = 1.f / sum;
        float* op = out + ((size_t)blk * 8 + tid) * 10;
        #pragma unroll
        for (int n = 0; n < 10; ++n) op[n] = e[n] * inv;
    }
}

extern "C" void kernel_launch(void* const* d_in, const int* in_sizes, int n_in,
                              void* d_out, int out_size, void* d_ws, size_t ws_size,
                              hipStream_t stream) {
    const float* x    = (const float*)d_in[0];
    const float* w1   = (const float*)d_in[1];
    const float* w2   = (const float*)d_in[2];
    const float* fw1  = (const float*)d_in[3];
    const float* fw2  = (const float*)d_in[4];
    const float* fc3w = (const float*)d_in[5];
    const float* fc3b = (const float*)d_in[6];
    float* outp = (float*)d_out;

    dim3 grid(16384 / 8), block(TH);
    hipLaunchKernelGGL(lenet_kernel, grid, block, 0, stream,
                       x, w1, w2, fw1, fw2, fc3w, fc3b, outp);
}

// Round 18
// 88.830 us; speedup vs baseline: 1.4238x; 1.0047x over previous
//
#include <hip/hip_runtime.h>
#include <hip/hip_fp16.h>
#include <math.h>

#define TH 256

typedef __attribute__((ext_vector_type(8))) _Float16 half8;
typedef __attribute__((ext_vector_type(4))) float floatx4;

// ---- LDS layout (halfs), 23696 h = 47392 B -> 3 blocks/CU ----
// P1  @0     : 8 img * 1178  ([img][y*84+x*6+ic] fp16)
// XI  @9424  : 8 img * 16 pairs * 66 + 64 pad = 8512  (xi[pair][x*2+par]; dead after conv1)
//    P2 @9424 (8*424) aliases XI after B2
// BT1 @17936 : 6 * 16 oc * 32 k = 3072 (conv1 weight mats; dead after Bw preload)
//    H1 @17936 (8*136) | H2 @19024 (8*104) | LOG floats @9928f (halfs 19856..20048)
// BT2 @21008 : 16 oc * 168 (conv2 weights)
#define P1_S   0
#define XI_S   9424
#define P2_S   9424
#define BT1_S  17936
#define H1_S   17936
#define H2_S   19024
#define LOG_F  9928       // float index
#define BT2_S  21008
#define LDS_F  11848      // floats = 47392 B

// weights row[kb..kb+7] -> fp16 frag via v_cvt_pkrtz; per-quad clamp keeps loads
// in bounds at the K tail (matching A slots are zero-padded).
static __device__ __forceinline__ half8 load_h8(const float* row, int kb, int K) {
    int b0 = (kb + 4 <= K) ? kb : (K - 8);
    int b1 = (kb + 8 <= K) ? (kb + 4) : (K - 8);
    float4 w0 = *(const float4*)(row + b0);
    float4 w1 = *(const float4*)(row + b1);
    union { unsigned u[4]; half8 v; } r;
    union { __fp16 __attribute__((ext_vector_type(2))) h; unsigned u; } c;
    c.h = __builtin_amdgcn_cvt_pkrtz(w0.x, w0.y); r.u[0] = c.u;
    c.h = __builtin_amdgcn_cvt_pkrtz(w0.z, w0.w); r.u[1] = c.u;
    c.h = __builtin_amdgcn_cvt_pkrtz(w1.x, w1.y); r.u[2] = c.u;
    c.h = __builtin_amdgcn_cvt_pkrtz(w1.z, w1.w); r.u[3] = c.u;
    return r.v;
}
// 16B A-frag from LDS half-index (4B-aligned only) via 4x b32
static __device__ __forceinline__ half8 lda(const int* p, int hidx) {
    int w = hidx >> 1;
    union { int4 i4; half8 h8; } a;
    a.i4.x = p[w]; a.i4.y = p[w + 1]; a.i4.z = p[w + 2]; a.i4.w = p[w + 3];
    return a.h8;
}

// NOTE: no min-waves arg (round 3: VGPR clamp -> scratch spill storm).
__global__ __launch_bounds__(TH) void lenet_kernel(
    const float* __restrict__ x,
    const float* __restrict__ w1g,
    const float* __restrict__ w2g,
    const float* __restrict__ fw1,
    const float* __restrict__ fw2,
    const float* __restrict__ fc3w,
    const float* __restrict__ fc3b,
    float* __restrict__ out)
{
    __shared__ __align__(16) float sf[LDS_F];
    short* sh = (short*)sf;
    __half* hp = (__half*)sf;
    const int* p1i = (const int*)sf;

    const int tid  = threadIdx.x;
    const int blk  = blockIdx.x;
    const int lane = tid & 63;
    const int wid  = tid >> 6;      // 0..3
    const int g    = lane >> 4;     // k-group selector of MFMA frags
    const int cn   = lane & 15;     // row(A)/col(B) selector
    const int pr   = cn & 7;        // conv2/fc img row
    const int dyr  = cn >> 3;       // conv2 pool-row packed into M

    // ---- stage: x -> xi row-pair layout; BT1 (conv1 w); BT2 (conv2 w) ----
    {
        float4 xreg[8];
        const float4* xg = (const float4*)(x + (size_t)blk * 8 * 1024);
        #pragma unroll
        for (int j = 0; j < 8; ++j) xreg[j] = xg[tid + j * TH];

        // BT1[b][oc][k]: k = xoff*2+par; weight row per (b,par) from nibble tables
        for (int e = tid; e < 3072; e += TH) {
            int b = e >> 9, r = e & 511;
            int oc = r >> 5, k = r & 31;
            int xoff = k >> 1, par = k & 1;
            int row = (int)(((par ? 0x531042u : 0x420531u) >> (4 * b)) & 15u) - 1;
            float v = 0.f;
            if (oc < 6 && xoff < 5 && row >= 0) v = w1g[oc * 25 + row * 5 + xoff];
            hp[BT1_S + e] = __float2half(v);
        }
        // BT2[oc][ky*32 + r], r = dx*6+ic (<30), zero-pad r=30,31
        for (int e = tid; e < 2560; e += TH) {
            int oc = e / 160, kk = e - oc * 160;
            int s = kk >> 5, r = kk & 31;
            float v = 0.f;
            if (r < 30) v = w2g[oc * 150 + (r % 6) * 25 + s * 5 + (r / 6)];
            hp[BT2_S + oc * 168 + kk] = __float2half(v);
        }
        // xi[m][pair][x*2+par], pair stride 66 (odd word), img stride 1056
        #pragma unroll
        for (int j = 0; j < 8; ++j) {
            int e = tid + j * TH;
            int m = e >> 8, rem = e & 255;
            int y = rem >> 3, x0 = (rem & 7) * 4;
            int base = XI_S + m * 1056 + (y >> 1) * 66 + (y & 1);
            float4 v = xreg[j];
            hp[base + (x0 + 0) * 2] = __float2half(v.x);
            hp[base + (x0 + 1) * 2] = __float2half(v.y);
            hp[base + (x0 + 2) * 2] = __float2half(v.z);
            hp[base + (x0 + 3) * 2] = __float2half(v.w);
        }
    }
    __syncthreads();                                   // B1

    // ======== conv1 via f16 MFMA: A = pixels (row=px), B = weights (col=oc) ========
    // K=32 = xoff(16)x par(2); window rows = 3 row-pairs; 6 B-matrices.
    {
        half8 Bw[6];
        #pragma unroll
        for (int b = 0; b < 6; ++b)
            Bw[b] = *(const half8*)(sh + BT1_S + b * 512 + cn * 32 + 8 * g);

        for (int mi = 0; mi < 2; ++mi) {
            int m = wid * 2 + mi;
            for (int cg = 0; cg < 2; ++cg) {
                int abase = XI_S + m * 1056 + cg * 32 + cn * 2 + 8 * g;
                half8 fr[3];
                fr[0] = lda(p1i, abase);
                fr[1] = lda(p1i, abase + 66);
                fr[2] = lda(p1i, abase + 132);
                #pragma unroll
                for (int i = 0; i < 14; ++i) {
                    half8 fa = fr[i % 3], fb = fr[(i + 1) % 3], fc = fr[(i + 2) % 3];
                    floatx4 aw0 = {0.f,0.f,0.f,0.f}, aw1 = {0.f,0.f,0.f,0.f};
                    aw0 = __builtin_amdgcn_mfma_f32_16x16x32_f16(fa, Bw[0], aw0, 0, 0, 0);
                    aw0 = __builtin_amdgcn_mfma_f32_16x16x32_f16(fb, Bw[1], aw0, 0, 0, 0);
                    aw0 = __builtin_amdgcn_mfma_f32_16x16x32_f16(fc, Bw[2], aw0, 0, 0, 0);
                    aw1 = __builtin_amdgcn_mfma_f32_16x16x32_f16(fa, Bw[3], aw1, 0, 0, 0);
                    aw1 = __builtin_amdgcn_mfma_f32_16x16x32_f16(fb, Bw[4], aw1, 0, 0, 0);
                    aw1 = __builtin_amdgcn_mfma_f32_16x16x32_f16(fc, Bw[5], aw1, 0, 0, 0);
                    if (i < 13) fr[i % 3] = lda(p1i, abase + (i + 3) * 66);
                    // D: col=oc=cn, row=px=4g+rg. Pool: rg pairs (cols), w0/w1 (rows).
                    if (cn < 6) {
                        int j0 = cg * 8 + 2 * g;
                        if (j0 < 14) {
                            float va = fmaxf(fmaxf(aw0[0], aw0[1]), fmaxf(aw1[0], aw1[1]));
                            hp[P1_S + m * 1178 + i * 84 + j0 * 6 + cn] =
                                __float2half(fmaxf(va, 0.f));
                            float vb = fmaxf(fmaxf(aw0[2], aw0[3]), fmaxf(aw1[2], aw1[3]));
                            hp[P1_S + m * 1178 + i * 84 + (j0 + 1) * 6 + cn] =
                                __float2half(fmaxf(vb, 0.f));
                        }
                    }
                }
            }
        }
    }
    __syncthreads();                                   // B2: p1 done, XI dead

    // ===== conv2 via f16 MFMA, dy-packed: M = img(8) x dy(2), N=16 oc, K=5x32 =====
    {
        half8 Breg[5];
        #pragma unroll
        for (int s = 0; s < 5; ++s)
            Breg[s] = *(const half8*)(sh + BT2_S + cn * 168 + s * 32 + 8 * g);

        if (tid < 192) {                               // p2 k-pad zeros [400,424)
            int im = tid / 24;
            sh[P2_S + im * 424 + 400 + (tid - im * 24)] = 0;
        }

        for (int w = wid; w < 25; w += 4) {            // pool windows (i,jx)
            int i = w / 5, jx = w - 5 * i;
            floatx4 a0 = {0.f,0.f,0.f,0.f}, a1 = {0.f,0.f,0.f,0.f};
            #pragma unroll
            for (int s = 0; s < 5; ++s) {
                #pragma unroll
                for (int dxp = 0; dxp < 2; ++dxp) {
                    int as = pr * 1178 + (2 * i + dyr + s) * 84 + (2 * jx + dxp) * 6 + 8 * g;
                    half8 a = lda(p1i, as);
                    floatx4* acc = dxp == 0 ? &a0 : &a1;
                    *acc = __builtin_amdgcn_mfma_f32_16x16x32_f16(a, Breg[s], *acc, 0, 0, 0);
                }
            }
            #pragma unroll
            for (int rg = 0; rg < 4; ++rg) {
                float v = fmaxf(a0[rg], a1[rg]);
                v = fmaxf(v, __shfl_xor(v, 32));
                if (g < 2) {
                    int im = 4 * g + rg;
                    hp[P2_S + im * 424 + cn * 25 + i * 5 + jx] = __float2half(fmaxf(v, 0.f));
                }
            }
        }
    }
    __syncthreads();                                   // B3: p2 done, BT1/BT2 dead

    // ================= fc1 via f16 MFMA: K=400(13 steps), N=120(8 tiles) =================
    {
        if (tid < 128)                                 // h1 pad zeros [120,136)
            sh[H1_S + (tid >> 4) * 136 + 120 + (tid & 15)] = 0;
        if (tid >= 96) {                               // h2 pad zeros [84,104): 160 elems
            int e = tid - 96, im = e / 20;
            sh[H2_S + im * 104 + 84 + (e - im * 20)] = 0;
        }
        for (int nt = wid; nt < 8; nt += 4) {
            floatx4 acc = {0.f,0.f,0.f,0.f};
            int n = nt * 16 + cn;
            const float* wrow = fw1 + (size_t)(n < 120 ? n : 119) * 400;
            for (int ks = 0; ks < 13; ++ks) {
                int kb = ks * 32 + 8 * g;
                half8 b = load_h8(wrow, kb, 400);
                half8 a = *(const half8*)(sh + P2_S + pr * 424 + kb);
                acc = __builtin_amdgcn_mfma_f32_16x16x32_f16(a, b, acc, 0, 0, 0);
            }
            if (g < 2 && n < 120) {
                #pragma unroll
                for (int rg = 0; rg < 4; ++rg)
                    hp[H1_S + (4 * g + rg) * 136 + n] = __float2half(fmaxf(acc[rg], 0.f));
            }
        }
    }
    __syncthreads();                                   // B4

    // ================= fc2 via f16 MFMA: K=120(4 steps), N=84(6 tiles) =================
    for (int nt = wid; nt < 6; nt += 4) {
        floatx4 acc = {0.f,0.f,0.f,0.f};
        int n = nt * 16 + cn;
        const float* wrow = fw2 + (size_t)(n < 84 ? n : 83) * 120;
        for (int ks = 0; ks < 4; ++ks) {
            int kb = ks * 32 + 8 * g;
            half8 b = load_h8(wrow, kb, 120);
            half8 a = *(const half8*)(sh + H1_S + pr * 136 + kb);
            acc = __builtin_amdgcn_mfma_f32_16x16x32_f16(a, b, acc, 0, 0, 0);
        }
        if (g < 2 && n < 84) {
            #pragma unroll
            for (int rg = 0; rg < 4; ++rg)
                hp[H2_S + (4 * g + rg) * 104 + n] = __float2half(fmaxf(acc[rg], 0.f));
        }
    }
    __syncthreads();                                   // B5

    // ================= fc3 via f16 MFMA: K=84(3 steps), N=10 + bias =================
    if (wid == 0) {
        floatx4 acc = {0.f,0.f,0.f,0.f};
        int n = cn;
        const float* wrow = fc3w + (size_t)(n < 10 ? n : 9) * 84;
        for (int ks = 0; ks < 3; ++ks) {
            int kb = ks * 32 + 8 * g;
            half8 b = load_h8(wrow, kb, 84);
            half8 a = *(const half8*)(sh + H2_S + pr * 104 + kb);
            acc = __builtin_amdgcn_mfma_f32_16x16x32_f16(a, b, acc, 0, 0, 0);
        }
        if (g < 2 && n < 10) {
            float bias = fc3b[n];
            #pragma unroll
            for (int rg = 0; rg < 4; ++rg)
                sf[LOG_F + (4 * g + rg) * 12 + n] = acc[rg] + bias;
        }
    }
    __syncthreads();                                   // B6

    // ================= softmax, one thread per image =================
    if (tid < 8) {
        const float* lg = sf + LOG_F + tid * 12;
        float mx = lg[0];
        #pragma unroll
        for (int n = 1; n < 10; ++n) mx = fmaxf(mx, lg[n]);
        float e[10]; float sum = 0.f;
        #pragma unroll
        for (int n = 0; n < 10; ++n) { e[n] = expf(lg[n] - mx); sum += e[n]; }
        float inv = 1.f / sum;
        float* op = out + ((size_t)blk * 8 + tid) * 10;
        #pragma unroll
        for (int n = 0; n < 10; ++n) op[n] = e[n] * inv;
    }
}

extern "C" void kernel_launch(void* const* d_in, const int* in_sizes, int n_in,
                              void* d_out, int out_size, void* d_ws, size_t ws_size,
                              hipStream_t stream) {
    const float* x    = (const float*)d_in[0];
    const float* w1   = (const float*)d_in[1];
    const float* w2   = (const float*)d_in[2];
    const float* fw1  = (const float*)d_in[3];
    const float* fw2  = (const float*)d_in[4];
    const float* fc3w = (const float*)d_in[5];
    const float* fc3b = (const float*)d_in[6];
    float* outp = (float*)d_out;

    dim3 grid(16384 / 8), block(TH);
    hipLaunchKernelGGL(lenet_kernel, grid, block, 0, stream,
                       x, w1, w2, fw1, fw2, fc3w, fc3b, outp);
}